// Round 1
// baseline (1887.961 us; speedup 1.0000x reference)
//
#include <hip/hip_runtime.h>
#include <math.h>

#define NN 30000
#define NE 200000
#define NT 3
#define NR 5
#define NH 8
#define DIM 256
#define ML 240
#define EPSF 1e-5f

__device__ __forceinline__ unsigned fkey(float f){
    unsigned b = __float_as_uint(f);
    return (b & 0x80000000u) ? ~b : (b | 0x80000000u);
}
__device__ __forceinline__ float funkey(unsigned u){
    return __uint_as_float((u & 0x80000000u) ? (u & 0x7fffffffu) : ~u);
}

// rte_vec[m,i] = sum_j emb[m,j]*rte_W[i,j] + rte_b[i]
__global__ void k_rtevec(const float* __restrict__ emb, const float* __restrict__ W,
                         const float* __restrict__ b, float* __restrict__ out){
    __shared__ float se[DIM];
    int m = blockIdx.x, i = threadIdx.x;
    se[i] = emb[m*DIM + i];
    __syncthreads();
    const float* wr = W + i*DIM;
    float acc = 0.f;
    #pragma unroll 8
    for (int j = 0; j < DIM; j += 4){
        float4 w = *reinterpret_cast<const float4*>(wr + j);
        acc += se[j]*w.x + se[j+1]*w.y + se[j+2]*w.z + se[j+3]*w.w;
    }
    out[m*DIM + i] = acc + b[i];
}

// rte_k[t,m,o] = sum_i rvec[m,i]*Wk[t][i,o]; same for rte_v
__global__ void k_rtekv(const float* __restrict__ rvec, const float* __restrict__ Wk,
                        const float* __restrict__ Wv, float* __restrict__ rk,
                        float* __restrict__ rv){
    __shared__ float sv[DIM];
    int m = blockIdx.x, t = blockIdx.y, o = threadIdx.x;
    sv[o] = rvec[m*DIM + o];
    __syncthreads();
    const float* wk = Wk + (size_t)t*DIM*DIM;
    const float* wv = Wv + (size_t)t*DIM*DIM;
    float ak = 0.f, av = 0.f;
    #pragma unroll 4
    for (int i = 0; i < DIM; i++){
        float s = sv[i];
        ak += s * wk[i*DIM + o];
        av += s * wv[i*DIM + o];
    }
    rk[(t*ML+m)*DIM + o] = ak;
    rv[(t*ML+m)*DIM + o] = av;
}

__global__ void k_bucket(const int* __restrict__ ntype, const int* __restrict__ etype,
                         int* __restrict__ ncnt, int* __restrict__ nlist,
                         int* __restrict__ ecnt, int* __restrict__ elist){
    int idx = blockIdx.x*blockDim.x + threadIdx.x;
    if (idx < NN){
        int t = ntype[idx];
        int p = atomicAdd(&ncnt[t], 1);
        nlist[t*NN + p] = idx;
    } else if (idx < NN + NE){
        int e = idx - NN;
        int r = etype[e];
        int p = atomicAdd(&ecnt[r], 1);
        elist[r*NE + p] = e;
    }
}

// Y[node, :] = X[node, :] @ W[t] + bias[t]  for nodes in nlist bucket t
__global__ __launch_bounds__(256) void k_proj(const float* __restrict__ X,
        const int* __restrict__ nlist, const int* __restrict__ ncnt,
        const float* __restrict__ W, const float* __restrict__ bias,
        float* __restrict__ Y){
    __shared__ float As[32][68];   // As[k][m]
    __shared__ float Bs[32][68];   // Bs[k][o]
    int t = blockIdx.z;
    int cnt = ncnt[t];
    int m0 = blockIdx.x * 64;
    if (m0 >= cnt) return;
    int o0 = blockIdx.y * 64;
    int tid = threadIdx.x;
    int mA = tid >> 3, kkA = (tid & 7) * 4;
    int nodeA  = (m0 + mA < cnt)      ? nlist[t*NN + m0 + mA]      : -1;
    int nodeA2 = (m0 + 32 + mA < cnt) ? nlist[t*NN + m0 + 32 + mA] : -1;
    int kkB = tid >> 4, oB = (tid & 15) * 4;
    const float* Wt = W + (size_t)t*DIM*DIM;
    float acc[16];
    #pragma unroll
    for (int i = 0; i < 16; i++) acc[i] = 0.f;
    int ty = tid >> 4, tx = tid & 15;
    for (int k0 = 0; k0 < DIM; k0 += 32){
        float4 a1 = {0,0,0,0}, a2 = {0,0,0,0};
        if (nodeA  >= 0) a1 = *reinterpret_cast<const float4*>(X + (size_t)nodeA*DIM  + k0 + kkA);
        if (nodeA2 >= 0) a2 = *reinterpret_cast<const float4*>(X + (size_t)nodeA2*DIM + k0 + kkA);
        float4 b1 = *reinterpret_cast<const float4*>(Wt + (size_t)(k0+kkB)*DIM    + o0 + oB);
        float4 b2 = *reinterpret_cast<const float4*>(Wt + (size_t)(k0+kkB+16)*DIM + o0 + oB);
        As[kkA+0][mA] = a1.x; As[kkA+1][mA] = a1.y; As[kkA+2][mA] = a1.z; As[kkA+3][mA] = a1.w;
        As[kkA+0][32+mA] = a2.x; As[kkA+1][32+mA] = a2.y; As[kkA+2][32+mA] = a2.z; As[kkA+3][32+mA] = a2.w;
        *reinterpret_cast<float4*>(&Bs[kkB][oB])    = b1;
        *reinterpret_cast<float4*>(&Bs[kkB+16][oB]) = b2;
        __syncthreads();
        #pragma unroll
        for (int k = 0; k < 32; k++){
            float4 a = *reinterpret_cast<const float4*>(&As[k][ty*4]);
            float4 b = *reinterpret_cast<const float4*>(&Bs[k][tx*4]);
            acc[0]  += a.x*b.x; acc[1]  += a.x*b.y; acc[2]  += a.x*b.z; acc[3]  += a.x*b.w;
            acc[4]  += a.y*b.x; acc[5]  += a.y*b.y; acc[6]  += a.y*b.z; acc[7]  += a.y*b.w;
            acc[8]  += a.z*b.x; acc[9]  += a.z*b.y; acc[10] += a.z*b.z; acc[11] += a.z*b.w;
            acc[12] += a.w*b.x; acc[13] += a.w*b.y; acc[14] += a.w*b.z; acc[15] += a.w*b.w;
        }
        __syncthreads();
    }
    float4 b4 = *reinterpret_cast<const float4*>(bias + t*DIM + o0 + tx*4);
    #pragma unroll
    for (int im = 0; im < 4; im++){
        int m = ty*4 + im;
        if (m0 + m < cnt){
            int node = nlist[t*NN + m0 + m];
            float4 r;
            r.x = acc[im*4+0] + b4.x;
            r.y = acc[im*4+1] + b4.y;
            r.z = acc[im*4+2] + b4.z;
            r.w = acc[im*4+3] + b4.w;
            *reinterpret_cast<float4*>(Y + (size_t)node*DIM + o0 + tx*4) = r;
        }
    }
}

// pass A: logits + segment max
__global__ __launch_bounds__(256) void k_passA(const float* __restrict__ qn,
        const float* __restrict__ kn, const float* __restrict__ rk,
        const int* __restrict__ elist, const int* __restrict__ ecnt,
        const int* __restrict__ esrc, const int* __restrict__ edst,
        const int* __restrict__ etime, const int* __restrict__ ntype,
        const float* __restrict__ rel_att, const float* __restrict__ rel_pri,
        float* __restrict__ logit, unsigned* __restrict__ mx){
    __shared__ int s_src[64], s_dst[64], s_tm[64], s_st[64], s_eid[64];
    __shared__ float ke[64][36], qe[64][36];
    int r = blockIdx.y;
    int cnt = ecnt[r];
    int e0 = blockIdx.x * 64;
    if (e0 >= cnt) return;
    int nE = min(64, cnt - e0);
    int tid = threadIdx.x;
    if (tid < 64){
        int e = elist[r*NE + e0 + (tid < nE ? tid : 0)];
        int sj = esrc[e];
        s_eid[tid] = e; s_src[tid] = sj; s_dst[tid] = edst[e];
        s_tm[tid] = etime[e]; s_st[tid] = ntype[sj];
    }
    __syncthreads();
    int f = tid & 31, mg = tid >> 5;
    const float inv = 0.17677669529663687f;  // 1/sqrt(32)
    for (int h = 0; h < NH; h++){
        #pragma unroll
        for (int u = 0; u < 2; u++){
            int fi = tid + u*256;
            int m = fi >> 3, c4 = (fi & 7) * 4;
            float4 kv = *reinterpret_cast<const float4*>(kn + (size_t)s_src[m]*DIM + h*32 + c4);
            float4 rv = *reinterpret_cast<const float4*>(rk + (size_t)(s_st[m]*ML + s_tm[m])*DIM + h*32 + c4);
            float4 qv = *reinterpret_cast<const float4*>(qn + (size_t)s_dst[m]*DIM + h*32 + c4);
            kv.x += rv.x; kv.y += rv.y; kv.z += rv.z; kv.w += rv.w;
            *reinterpret_cast<float4*>(&ke[m][c4]) = kv;
            *reinterpret_cast<float4*>(&qe[m][c4]) = qv;
        }
        __syncthreads();
        float rf[32];
        const float* relb = rel_att + (size_t)(r*NH + h)*1024;
        #pragma unroll
        for (int d = 0; d < 32; d++) rf[d] = relb[d*32 + f];
        float pri = rel_pri[r*NH + h] * inv;
        #pragma unroll
        for (int mi = 0; mi < 8; mi++){
            int m = mg*8 + mi;
            float acc = 0.f;
            #pragma unroll
            for (int d4 = 0; d4 < 8; d4++){
                float4 k4 = *reinterpret_cast<const float4*>(&ke[m][d4*4]);
                acc += k4.x*rf[d4*4] + k4.y*rf[d4*4+1] + k4.z*rf[d4*4+2] + k4.w*rf[d4*4+3];
            }
            float v = acc * qe[m][f];
            v += __shfl_xor(v, 1);
            v += __shfl_xor(v, 2);
            v += __shfl_xor(v, 4);
            v += __shfl_xor(v, 8);
            v += __shfl_xor(v, 16);
            if (f == 0 && m < nE){
                float lv = v * pri;
                logit[(size_t)s_eid[m]*NH + h] = lv;
                atomicMax(&mx[s_dst[m]*NH + h], fkey(lv));
            }
        }
        __syncthreads();
    }
}

// pass B: unnormalized exp-weighted message aggregation + denominator
__global__ __launch_bounds__(256) void k_passB(const float* __restrict__ vn,
        const float* __restrict__ rv, const int* __restrict__ elist,
        const int* __restrict__ ecnt, const int* __restrict__ esrc,
        const int* __restrict__ edst, const int* __restrict__ etime,
        const int* __restrict__ ntype, const float* __restrict__ rel_msg,
        const float* __restrict__ logit, const unsigned* __restrict__ mx,
        float* __restrict__ den, float* __restrict__ aggr){
    __shared__ int s_src[64], s_dst[64], s_tm[64], s_st[64], s_eid[64];
    __shared__ float ve[64][36];
    int r = blockIdx.y;
    int cnt = ecnt[r];
    int e0 = blockIdx.x * 64;
    if (e0 >= cnt) return;
    int nE = min(64, cnt - e0);
    int tid = threadIdx.x;
    if (tid < 64){
        int e = elist[r*NE + e0 + (tid < nE ? tid : 0)];
        int sj = esrc[e];
        s_eid[tid] = e; s_src[tid] = sj; s_dst[tid] = edst[e];
        s_tm[tid] = etime[e]; s_st[tid] = ntype[sj];
    }
    __syncthreads();
    int f = tid & 31, mg = tid >> 5;
    for (int h = 0; h < NH; h++){
        #pragma unroll
        for (int u = 0; u < 2; u++){
            int fi = tid + u*256;
            int m = fi >> 3, c4 = (fi & 7) * 4;
            float4 vv = *reinterpret_cast<const float4*>(vn + (size_t)s_src[m]*DIM + h*32 + c4);
            float4 rr = *reinterpret_cast<const float4*>(rv + (size_t)(s_st[m]*ML + s_tm[m])*DIM + h*32 + c4);
            vv.x += rr.x; vv.y += rr.y; vv.z += rr.z; vv.w += rr.w;
            *reinterpret_cast<float4*>(&ve[m][c4]) = vv;
        }
        __syncthreads();
        float rf[32];
        const float* relb = rel_msg + (size_t)(r*NH + h)*1024;
        #pragma unroll
        for (int d = 0; d < 32; d++) rf[d] = relb[d*32 + f];
        #pragma unroll
        for (int mi = 0; mi < 8; mi++){
            int m = mg*8 + mi;
            float acc = 0.f;
            #pragma unroll
            for (int d4 = 0; d4 < 8; d4++){
                float4 v4 = *reinterpret_cast<const float4*>(&ve[m][d4*4]);
                acc += v4.x*rf[d4*4] + v4.y*rf[d4*4+1] + v4.z*rf[d4*4+2] + v4.w*rf[d4*4+3];
            }
            if (m < nE){
                float lg = logit[(size_t)s_eid[m]*NH + h];
                float mv = funkey(mx[s_dst[m]*NH + h]);
                float ex = __expf(lg - mv);
                atomicAdd(&aggr[(size_t)s_dst[m]*DIM + h*32 + f], acc*ex);
                if (f == 0) atomicAdd(&den[s_dst[m]*NH + h], ex);
            }
        }
        __syncthreads();
    }
}

__global__ void k_aggdiv(float* __restrict__ aggr, const float* __restrict__ den){
    int idx = blockIdx.x*256 + threadIdx.x;
    int n = idx >> 8, c = idx & 255;
    float d = den[n*NH + (c >> 5)];
    if (d > 0.f) aggr[idx] /= d;
}

__global__ __launch_bounds__(256) void k_epi(const float* __restrict__ trans,
        const float* __restrict__ x, const int* __restrict__ ntype,
        const float* __restrict__ skip, const float* __restrict__ g,
        const float* __restrict__ b, float* __restrict__ out){
    __shared__ float r1[4], r2[4];
    int n = blockIdx.x, c = threadIdx.x;
    int t = ntype[n];
    float alpha = 1.f / (1.f + expf(-skip[t]));
    float mixed = trans[(size_t)n*DIM + c]*alpha + x[(size_t)n*DIM + c]*(1.f - alpha);
    float s = mixed, q = mixed*mixed;
    #pragma unroll
    for (int off = 32; off >= 1; off >>= 1){
        s += __shfl_down(s, off);
        q += __shfl_down(q, off);
    }
    int w = c >> 6;
    if ((c & 63) == 0){ r1[w] = s; r2[w] = q; }
    __syncthreads();
    float S  = r1[0]+r1[1]+r1[2]+r1[3];
    float S2 = r2[0]+r2[1]+r2[2]+r2[3];
    float mu = S * (1.f/DIM);
    float var = S2 * (1.f/DIM) - mu*mu;
    out[(size_t)n*DIM + c] = (mixed - mu) * rsqrtf(var + EPSF) * g[t*DIM + c] + b[t*DIM + c];
}

extern "C" void kernel_launch(void* const* d_in, const int* in_sizes, int n_in,
                              void* d_out, int out_size, void* d_ws, size_t ws_size,
                              hipStream_t stream){
    const float* node_inp = (const float*)d_in[0];
    const float* Wk  = (const float*)d_in[1];
    const float* bk  = (const float*)d_in[2];
    const float* Wq  = (const float*)d_in[3];
    const float* bq  = (const float*)d_in[4];
    const float* Wv  = (const float*)d_in[5];
    const float* bv  = (const float*)d_in[6];
    const float* Wa  = (const float*)d_in[7];
    const float* ba  = (const float*)d_in[8];
    const float* ln_g = (const float*)d_in[9];
    const float* ln_b = (const float*)d_in[10];
    const float* rel_pri = (const float*)d_in[11];
    const float* rel_att = (const float*)d_in[12];
    const float* rel_msg = (const float*)d_in[13];
    const float* skip  = (const float*)d_in[14];
    const float* rte_W = (const float*)d_in[15];
    const float* rte_b = (const float*)d_in[16];
    const float* rte_emb = (const float*)d_in[17];
    const int* ntype = (const int*)d_in[18];
    const int* eidx  = (const int*)d_in[19];
    const int* etype = (const int*)d_in[20];
    const int* etime = (const int*)d_in[21];
    const int* esrc = eidx;
    const int* edst = eidx + NE;

    float* ws = (float*)d_ws;
    size_t o_aggr = 0;
    size_t o_mx   = o_aggr + (size_t)NN*DIM;
    size_t o_den  = o_mx   + (size_t)NN*NH;
    size_t o_cnt  = o_den  + (size_t)NN*NH;
    size_t zeroEnd= o_cnt  + 16;
    size_t o_q    = zeroEnd + 16;
    size_t o_k    = o_q    + (size_t)NN*DIM;
    size_t o_rvec = o_k    + (size_t)NN*DIM;
    size_t o_rk   = o_rvec + (size_t)ML*DIM;
    size_t o_rv   = o_rk   + (size_t)NT*ML*DIM;
    size_t o_logit= o_rv   + (size_t)NT*ML*DIM;
    size_t o_nlist= o_logit+ (size_t)NE*NH;
    size_t o_elist= o_nlist+ (size_t)NT*NN;

    float* aggr = ws + o_aggr;
    unsigned* mx = (unsigned*)(ws + o_mx);
    float* den = ws + o_den;
    int* ncnt = (int*)(ws + o_cnt);
    int* ecnt = ncnt + 8;
    float* qn = ws + o_q;
    float* kn = ws + o_k;
    float* rvec = ws + o_rvec;
    float* rk = ws + o_rk;
    float* rv = ws + o_rv;
    float* logit = ws + o_logit;
    int* nlist = (int*)(ws + o_nlist);
    int* elist = (int*)(ws + o_elist);
    float* vn = qn;      // alias: q dead after pass A
    float* trans = kn;   // alias: k dead after pass A
    float* out = (float*)d_out;

    hipMemsetAsync(d_ws, 0, zeroEnd * sizeof(float), stream);
    k_rtevec<<<ML, 256, 0, stream>>>(rte_emb, rte_W, rte_b, rvec);
    k_rtekv<<<dim3(ML, NT), 256, 0, stream>>>(rvec, Wk, Wv, rk, rv);
    k_bucket<<<(NN+NE+255)/256, 256, 0, stream>>>(ntype, etype, ncnt, nlist, ecnt, elist);
    dim3 pgrid((NN+63)/64, 4, NT);
    k_proj<<<pgrid, 256, 0, stream>>>(node_inp, nlist, ncnt, Wq, bq, qn);
    k_proj<<<pgrid, 256, 0, stream>>>(node_inp, nlist, ncnt, Wk, bk, kn);
    dim3 egrid((NE+63)/64, NR);
    k_passA<<<egrid, 256, 0, stream>>>(qn, kn, rk, elist, ecnt, esrc, edst, etime, ntype,
                                       rel_att, rel_pri, logit, mx);
    k_proj<<<pgrid, 256, 0, stream>>>(node_inp, nlist, ncnt, Wv, bv, vn);
    k_passB<<<egrid, 256, 0, stream>>>(vn, rv, elist, ecnt, esrc, edst, etime, ntype,
                                       rel_msg, logit, mx, den, aggr);
    k_aggdiv<<<(NN*DIM)/256, 256, 0, stream>>>(aggr, den);
    k_proj<<<pgrid, 256, 0, stream>>>(aggr, nlist, ncnt, Wa, ba, trans);
    k_epi<<<NN, 256, 0, stream>>>(trans, node_inp, ntype, skip, ln_g, ln_b, out);
}

// Round 2
// 765.963 us; speedup vs baseline: 2.4648x; 2.4648x over previous
//
#include <hip/hip_runtime.h>
#include <math.h>

#define NN 30000
#define NE 200000
#define NT 3
#define NR 5
#define NH 8
#define DIM 256
#define ML 240
#define EPSF 1e-5f

__device__ __forceinline__ unsigned fkey(float f){
    unsigned b = __float_as_uint(f);
    return (b & 0x80000000u) ? ~b : (b | 0x80000000u);
}
__device__ __forceinline__ float funkey(unsigned u){
    return __uint_as_float((u & 0x80000000u) ? (u & 0x7fffffffu) : ~u);
}

// rte_vec[m,i] = sum_j emb[m,j]*rte_W[i,j] + rte_b[i]
__global__ void k_rtevec(const float* __restrict__ emb, const float* __restrict__ W,
                         const float* __restrict__ b, float* __restrict__ out){
    __shared__ float se[DIM];
    int m = blockIdx.x, i = threadIdx.x;
    se[i] = emb[m*DIM + i];
    __syncthreads();
    const float* wr = W + i*DIM;
    float acc = 0.f;
    #pragma unroll 8
    for (int j = 0; j < DIM; j += 4){
        float4 w = *reinterpret_cast<const float4*>(wr + j);
        acc += se[j]*w.x + se[j+1]*w.y + se[j+2]*w.z + se[j+3]*w.w;
    }
    out[m*DIM + i] = acc + b[i];
}

// rte_k[t,m,o] = sum_i rvec[m,i]*Wk[t][i,o]; same for rte_v
__global__ void k_rtekv(const float* __restrict__ rvec, const float* __restrict__ Wk,
                        const float* __restrict__ Wv, float* __restrict__ rk,
                        float* __restrict__ rv){
    __shared__ float sv[DIM];
    int m = blockIdx.x, t = blockIdx.y, o = threadIdx.x;
    sv[o] = rvec[m*DIM + o];
    __syncthreads();
    const float* wk = Wk + (size_t)t*DIM*DIM;
    const float* wv = Wv + (size_t)t*DIM*DIM;
    float ak = 0.f, av = 0.f;
    #pragma unroll 4
    for (int i = 0; i < DIM; i++){
        float s = sv[i];
        ak += s * wk[i*DIM + o];
        av += s * wv[i*DIM + o];
    }
    rk[(t*ML+m)*DIM + o] = ak;
    rv[(t*ML+m)*DIM + o] = av;
}

// two-level bucketing: LDS histogram + one global atomic per (block,key)
__global__ void k_bucket(const int* __restrict__ ntype, const int* __restrict__ etype,
                         int* __restrict__ ncnt, int* __restrict__ nlist,
                         int* __restrict__ ecnt, int* __restrict__ elist){
    __shared__ int lc[8];
    __shared__ int lb[8];
    int tid = threadIdx.x;
    if (tid < 8) lc[tid] = 0;
    __syncthreads();
    int idx = blockIdx.x*256 + tid;
    int key = -1, lpos = 0;
    if (idx < NN){
        key = ntype[idx];
        lpos = atomicAdd(&lc[key], 1);
    } else if (idx < NN + NE){
        key = NT + etype[idx - NN];
        lpos = atomicAdd(&lc[key], 1);
    }
    __syncthreads();
    if (tid < 8 && lc[tid] > 0){
        lb[tid] = atomicAdd(tid < NT ? &ncnt[tid] : &ecnt[tid - NT], lc[tid]);
    }
    __syncthreads();
    if (idx < NN){
        nlist[key*NN + lb[key] + lpos] = idx;
    } else if (idx < NN + NE){
        elist[(key - NT)*NE + lb[key] + lpos] = idx - NN;
    }
}

// Y[node, :] = X[node, :] @ W[t] + bias[t]  for nodes in nlist bucket t
__global__ __launch_bounds__(256) void k_proj(const float* __restrict__ X,
        const int* __restrict__ nlist, const int* __restrict__ ncnt,
        const float* __restrict__ W, const float* __restrict__ bias,
        float* __restrict__ Y){
    __shared__ float As[32][68];   // As[k][m]
    __shared__ float Bs[32][68];   // Bs[k][o]
    int t = blockIdx.z;
    int cnt = ncnt[t];
    int m0 = blockIdx.x * 64;
    if (m0 >= cnt) return;
    int o0 = blockIdx.y * 64;
    int tid = threadIdx.x;
    int mA = tid >> 3, kkA = (tid & 7) * 4;
    int nodeA  = (m0 + mA < cnt)      ? nlist[t*NN + m0 + mA]      : -1;
    int nodeA2 = (m0 + 32 + mA < cnt) ? nlist[t*NN + m0 + 32 + mA] : -1;
    int kkB = tid >> 4, oB = (tid & 15) * 4;
    const float* Wt = W + (size_t)t*DIM*DIM;
    float acc[16];
    #pragma unroll
    for (int i = 0; i < 16; i++) acc[i] = 0.f;
    int ty = tid >> 4, tx = tid & 15;
    for (int k0 = 0; k0 < DIM; k0 += 32){
        float4 a1 = {0,0,0,0}, a2 = {0,0,0,0};
        if (nodeA  >= 0) a1 = *reinterpret_cast<const float4*>(X + (size_t)nodeA*DIM  + k0 + kkA);
        if (nodeA2 >= 0) a2 = *reinterpret_cast<const float4*>(X + (size_t)nodeA2*DIM + k0 + kkA);
        float4 b1 = *reinterpret_cast<const float4*>(Wt + (size_t)(k0+kkB)*DIM    + o0 + oB);
        float4 b2 = *reinterpret_cast<const float4*>(Wt + (size_t)(k0+kkB+16)*DIM + o0 + oB);
        As[kkA+0][mA] = a1.x; As[kkA+1][mA] = a1.y; As[kkA+2][mA] = a1.z; As[kkA+3][mA] = a1.w;
        As[kkA+0][32+mA] = a2.x; As[kkA+1][32+mA] = a2.y; As[kkA+2][32+mA] = a2.z; As[kkA+3][32+mA] = a2.w;
        *reinterpret_cast<float4*>(&Bs[kkB][oB])    = b1;
        *reinterpret_cast<float4*>(&Bs[kkB+16][oB]) = b2;
        __syncthreads();
        #pragma unroll
        for (int k = 0; k < 32; k++){
            float4 a = *reinterpret_cast<const float4*>(&As[k][ty*4]);
            float4 b = *reinterpret_cast<const float4*>(&Bs[k][tx*4]);
            acc[0]  += a.x*b.x; acc[1]  += a.x*b.y; acc[2]  += a.x*b.z; acc[3]  += a.x*b.w;
            acc[4]  += a.y*b.x; acc[5]  += a.y*b.y; acc[6]  += a.y*b.z; acc[7]  += a.y*b.w;
            acc[8]  += a.z*b.x; acc[9]  += a.z*b.y; acc[10] += a.z*b.z; acc[11] += a.z*b.w;
            acc[12] += a.w*b.x; acc[13] += a.w*b.y; acc[14] += a.w*b.z; acc[15] += a.w*b.w;
        }
        __syncthreads();
    }
    float4 b4 = *reinterpret_cast<const float4*>(bias + t*DIM + o0 + tx*4);
    #pragma unroll
    for (int im = 0; im < 4; im++){
        int m = ty*4 + im;
        if (m0 + m < cnt){
            int node = nlist[t*NN + m0 + m];
            float4 r;
            r.x = acc[im*4+0] + b4.x;
            r.y = acc[im*4+1] + b4.y;
            r.z = acc[im*4+2] + b4.z;
            r.w = acc[im*4+3] + b4.w;
            *reinterpret_cast<float4*>(Y + (size_t)node*DIM + o0 + tx*4) = r;
        }
    }
}

// pass A: logits + segment max
__global__ __launch_bounds__(256) void k_passA(const float* __restrict__ qn,
        const float* __restrict__ kn, const float* __restrict__ rk,
        const int* __restrict__ elist, const int* __restrict__ ecnt,
        const int* __restrict__ esrc, const int* __restrict__ edst,
        const int* __restrict__ etime, const int* __restrict__ ntype,
        const float* __restrict__ rel_att, const float* __restrict__ rel_pri,
        float* __restrict__ logit, unsigned* __restrict__ mx){
    __shared__ int s_src[64], s_dst[64], s_tm[64], s_st[64], s_eid[64];
    __shared__ float ke[64][36], qe[64][36];
    int r = blockIdx.y;
    int cnt = ecnt[r];
    int e0 = blockIdx.x * 64;
    if (e0 >= cnt) return;
    int nE = min(64, cnt - e0);
    int tid = threadIdx.x;
    if (tid < 64){
        int e = elist[r*NE + e0 + (tid < nE ? tid : 0)];
        int sj = esrc[e];
        s_eid[tid] = e; s_src[tid] = sj; s_dst[tid] = edst[e];
        s_tm[tid] = etime[e]; s_st[tid] = ntype[sj];
    }
    __syncthreads();
    int f = tid & 31, mg = tid >> 5;
    const float inv = 0.17677669529663687f;  // 1/sqrt(32)
    for (int h = 0; h < NH; h++){
        #pragma unroll
        for (int u = 0; u < 2; u++){
            int fi = tid + u*256;
            int m = fi >> 3, c4 = (fi & 7) * 4;
            float4 kv = *reinterpret_cast<const float4*>(kn + (size_t)s_src[m]*DIM + h*32 + c4);
            float4 rv = *reinterpret_cast<const float4*>(rk + (size_t)(s_st[m]*ML + s_tm[m])*DIM + h*32 + c4);
            float4 qv = *reinterpret_cast<const float4*>(qn + (size_t)s_dst[m]*DIM + h*32 + c4);
            kv.x += rv.x; kv.y += rv.y; kv.z += rv.z; kv.w += rv.w;
            *reinterpret_cast<float4*>(&ke[m][c4]) = kv;
            *reinterpret_cast<float4*>(&qe[m][c4]) = qv;
        }
        __syncthreads();
        float rf[32];
        const float* relb = rel_att + (size_t)(r*NH + h)*1024;
        #pragma unroll
        for (int d = 0; d < 32; d++) rf[d] = relb[d*32 + f];
        float pri = rel_pri[r*NH + h] * inv;
        #pragma unroll
        for (int mi = 0; mi < 8; mi++){
            int m = mg*8 + mi;
            float acc = 0.f;
            #pragma unroll
            for (int d4 = 0; d4 < 8; d4++){
                float4 k4 = *reinterpret_cast<const float4*>(&ke[m][d4*4]);
                acc += k4.x*rf[d4*4] + k4.y*rf[d4*4+1] + k4.z*rf[d4*4+2] + k4.w*rf[d4*4+3];
            }
            float v = acc * qe[m][f];
            v += __shfl_xor(v, 1);
            v += __shfl_xor(v, 2);
            v += __shfl_xor(v, 4);
            v += __shfl_xor(v, 8);
            v += __shfl_xor(v, 16);
            if (f == 0 && m < nE){
                float lv = v * pri;
                logit[(size_t)s_eid[m]*NH + h] = lv;
                atomicMax(&mx[s_dst[m]*NH + h], fkey(lv));
            }
        }
        __syncthreads();
    }
}

// pass B: unnormalized exp-weighted message aggregation + denominator
__global__ __launch_bounds__(256) void k_passB(const float* __restrict__ vn,
        const float* __restrict__ rv, const int* __restrict__ elist,
        const int* __restrict__ ecnt, const int* __restrict__ esrc,
        const int* __restrict__ edst, const int* __restrict__ etime,
        const int* __restrict__ ntype, const float* __restrict__ rel_msg,
        const float* __restrict__ logit, const unsigned* __restrict__ mx,
        float* __restrict__ den, float* __restrict__ aggr){
    __shared__ int s_src[64], s_dst[64], s_tm[64], s_st[64], s_eid[64];
    __shared__ float ve[64][36];
    int r = blockIdx.y;
    int cnt = ecnt[r];
    int e0 = blockIdx.x * 64;
    if (e0 >= cnt) return;
    int nE = min(64, cnt - e0);
    int tid = threadIdx.x;
    if (tid < 64){
        int e = elist[r*NE + e0 + (tid < nE ? tid : 0)];
        int sj = esrc[e];
        s_eid[tid] = e; s_src[tid] = sj; s_dst[tid] = edst[e];
        s_tm[tid] = etime[e]; s_st[tid] = ntype[sj];
    }
    __syncthreads();
    int f = tid & 31, mg = tid >> 5;
    for (int h = 0; h < NH; h++){
        #pragma unroll
        for (int u = 0; u < 2; u++){
            int fi = tid + u*256;
            int m = fi >> 3, c4 = (fi & 7) * 4;
            float4 vv = *reinterpret_cast<const float4*>(vn + (size_t)s_src[m]*DIM + h*32 + c4);
            float4 rr = *reinterpret_cast<const float4*>(rv + (size_t)(s_st[m]*ML + s_tm[m])*DIM + h*32 + c4);
            vv.x += rr.x; vv.y += rr.y; vv.z += rr.z; vv.w += rr.w;
            *reinterpret_cast<float4*>(&ve[m][c4]) = vv;
        }
        __syncthreads();
        float rf[32];
        const float* relb = rel_msg + (size_t)(r*NH + h)*1024;
        #pragma unroll
        for (int d = 0; d < 32; d++) rf[d] = relb[d*32 + f];
        #pragma unroll
        for (int mi = 0; mi < 8; mi++){
            int m = mg*8 + mi;
            float acc = 0.f;
            #pragma unroll
            for (int d4 = 0; d4 < 8; d4++){
                float4 v4 = *reinterpret_cast<const float4*>(&ve[m][d4*4]);
                acc += v4.x*rf[d4*4] + v4.y*rf[d4*4+1] + v4.z*rf[d4*4+2] + v4.w*rf[d4*4+3];
            }
            if (m < nE){
                float lg = logit[(size_t)s_eid[m]*NH + h];
                float mv = funkey(mx[s_dst[m]*NH + h]);
                float ex = __expf(lg - mv);
                atomicAdd(&aggr[(size_t)s_dst[m]*DIM + h*32 + f], acc*ex);
                if (f == 0) atomicAdd(&den[s_dst[m]*NH + h], ex);
            }
        }
        __syncthreads();
    }
}

__global__ void k_aggdiv(float* __restrict__ aggr, const float* __restrict__ den){
    int idx = blockIdx.x*256 + threadIdx.x;
    int n = idx >> 8, c = idx & 255;
    float d = den[n*NH + (c >> 5)];
    if (d > 0.f) aggr[idx] /= d;
}

__global__ __launch_bounds__(256) void k_epi(const float* __restrict__ trans,
        const float* __restrict__ x, const int* __restrict__ ntype,
        const float* __restrict__ skip, const float* __restrict__ g,
        const float* __restrict__ b, float* __restrict__ out){
    __shared__ float r1[4], r2[4];
    int n = blockIdx.x, c = threadIdx.x;
    int t = ntype[n];
    float alpha = 1.f / (1.f + expf(-skip[t]));
    float mixed = trans[(size_t)n*DIM + c]*alpha + x[(size_t)n*DIM + c]*(1.f - alpha);
    float s = mixed, q = mixed*mixed;
    #pragma unroll
    for (int off = 32; off >= 1; off >>= 1){
        s += __shfl_down(s, off);
        q += __shfl_down(q, off);
    }
    int w = c >> 6;
    if ((c & 63) == 0){ r1[w] = s; r2[w] = q; }
    __syncthreads();
    float S  = r1[0]+r1[1]+r1[2]+r1[3];
    float S2 = r2[0]+r2[1]+r2[2]+r2[3];
    float mu = S * (1.f/DIM);
    float var = S2 * (1.f/DIM) - mu*mu;
    out[(size_t)n*DIM + c] = (mixed - mu) * rsqrtf(var + EPSF) * g[t*DIM + c] + b[t*DIM + c];
}

extern "C" void kernel_launch(void* const* d_in, const int* in_sizes, int n_in,
                              void* d_out, int out_size, void* d_ws, size_t ws_size,
                              hipStream_t stream){
    const float* node_inp = (const float*)d_in[0];
    const float* Wk  = (const float*)d_in[1];
    const float* bk  = (const float*)d_in[2];
    const float* Wq  = (const float*)d_in[3];
    const float* bq  = (const float*)d_in[4];
    const float* Wv  = (const float*)d_in[5];
    const float* bv  = (const float*)d_in[6];
    const float* Wa  = (const float*)d_in[7];
    const float* ba  = (const float*)d_in[8];
    const float* ln_g = (const float*)d_in[9];
    const float* ln_b = (const float*)d_in[10];
    const float* rel_pri = (const float*)d_in[11];
    const float* rel_att = (const float*)d_in[12];
    const float* rel_msg = (const float*)d_in[13];
    const float* skip  = (const float*)d_in[14];
    const float* rte_W = (const float*)d_in[15];
    const float* rte_b = (const float*)d_in[16];
    const float* rte_emb = (const float*)d_in[17];
    const int* ntype = (const int*)d_in[18];
    const int* eidx  = (const int*)d_in[19];
    const int* etype = (const int*)d_in[20];
    const int* etime = (const int*)d_in[21];
    const int* esrc = eidx;
    const int* edst = eidx + NE;

    float* ws = (float*)d_ws;
    size_t o_aggr = 0;
    size_t o_mx   = o_aggr + (size_t)NN*DIM;
    size_t o_den  = o_mx   + (size_t)NN*NH;
    size_t o_cnt  = o_den  + (size_t)NN*NH;
    size_t zeroEnd= o_cnt  + 16;
    size_t o_q    = zeroEnd + 16;
    size_t o_k    = o_q    + (size_t)NN*DIM;
    size_t o_rvec = o_k    + (size_t)NN*DIM;
    size_t o_rk   = o_rvec + (size_t)ML*DIM;
    size_t o_rv   = o_rk   + (size_t)NT*ML*DIM;
    size_t o_logit= o_rv   + (size_t)NT*ML*DIM;
    size_t o_nlist= o_logit+ (size_t)NE*NH;
    size_t o_elist= o_nlist+ (size_t)NT*NN;

    float* aggr = ws + o_aggr;
    unsigned* mx = (unsigned*)(ws + o_mx);
    float* den = ws + o_den;
    int* ncnt = (int*)(ws + o_cnt);
    int* ecnt = ncnt + 8;
    float* qn = ws + o_q;
    float* kn = ws + o_k;
    float* rvec = ws + o_rvec;
    float* rk = ws + o_rk;
    float* rv = ws + o_rv;
    float* logit = ws + o_logit;
    int* nlist = (int*)(ws + o_nlist);
    int* elist = (int*)(ws + o_elist);
    float* vn = qn;      // alias: q dead after pass A
    float* trans = kn;   // alias: k dead after pass A
    float* out = (float*)d_out;

    hipMemsetAsync(d_ws, 0, zeroEnd * sizeof(float), stream);
    k_rtevec<<<ML, 256, 0, stream>>>(rte_emb, rte_W, rte_b, rvec);
    k_rtekv<<<dim3(ML, NT), 256, 0, stream>>>(rvec, Wk, Wv, rk, rv);
    k_bucket<<<(NN+NE+255)/256, 256, 0, stream>>>(ntype, etype, ncnt, nlist, ecnt, elist);
    dim3 pgrid((NN+63)/64, 4, NT);
    k_proj<<<pgrid, 256, 0, stream>>>(node_inp, nlist, ncnt, Wq, bq, qn);
    k_proj<<<pgrid, 256, 0, stream>>>(node_inp, nlist, ncnt, Wk, bk, kn);
    dim3 egrid((NE+63)/64, NR);
    k_passA<<<egrid, 256, 0, stream>>>(qn, kn, rk, elist, ecnt, esrc, edst, etime, ntype,
                                       rel_att, rel_pri, logit, mx);
    k_proj<<<pgrid, 256, 0, stream>>>(node_inp, nlist, ncnt, Wv, bv, vn);
    k_passB<<<egrid, 256, 0, stream>>>(vn, rv, elist, ecnt, esrc, edst, etime, ntype,
                                       rel_msg, logit, mx, den, aggr);
    k_aggdiv<<<(NN*DIM)/256, 256, 0, stream>>>(aggr, den);
    k_proj<<<pgrid, 256, 0, stream>>>(aggr, nlist, ncnt, Wa, ba, trans);
    k_epi<<<NN, 256, 0, stream>>>(trans, node_inp, ntype, skip, ln_g, ln_b, out);
}

// Round 4
// 581.966 us; speedup vs baseline: 3.2441x; 1.3162x over previous
//
#include <hip/hip_runtime.h>
#include <hip/hip_bf16.h>
#include <math.h>

#define NN 30000
#define NE 200000
#define NT 3
#define NR 5
#define NH 8
#define DIM 256
#define ML 240
#define EPSF 1e-5f

typedef __attribute__((ext_vector_type(8))) short short8v;
typedef __attribute__((ext_vector_type(4))) float f32x4;

__device__ __forceinline__ unsigned fkey(float f){
    unsigned b = __float_as_uint(f);
    return (b & 0x80000000u) ? ~b : (b | 0x80000000u);
}
__device__ __forceinline__ float funkey(unsigned u){
    return __uint_as_float((u & 0x80000000u) ? (u & 0x7fffffffu) : ~u);
}
__device__ __forceinline__ unsigned short f2bf(float f){
    unsigned b = __float_as_uint(f);
    unsigned r = (b + 0x7FFFu + ((b >> 16) & 1u)) >> 16;
    return (unsigned short)r;
}

// ---------------- f32 -> bf16 bulk convert (8 elems/thread) ----------------
__global__ void k_cvt(const float* __restrict__ in, unsigned short* __restrict__ out){
    int idx = blockIdx.x*256 + threadIdx.x;
    const float4* s = reinterpret_cast<const float4*>(in + (size_t)idx*8);
    float4 a = s[0], b = s[1];
    unsigned short t[8];
    t[0]=f2bf(a.x); t[1]=f2bf(a.y); t[2]=f2bf(a.z); t[3]=f2bf(a.w);
    t[4]=f2bf(b.x); t[5]=f2bf(b.y); t[6]=f2bf(b.z); t[7]=f2bf(b.w);
    *reinterpret_cast<uint4*>(out + (size_t)idx*8) = *reinterpret_cast<uint4*>(t);
}

// ---------- W [NT][256][256] f32 -> Wt [NT][256(o)][256(i)] bf16 -----------
__global__ __launch_bounds__(256) void k_cvt_w(const float* __restrict__ W,
                                               unsigned short* __restrict__ Wt){
    __shared__ float S[64][65];
    int t = blockIdx.z;
    int i0 = blockIdx.x * 64, o0 = blockIdx.y * 64;
    int th = threadIdx.x;
    int r = th >> 2, c0 = (th & 3) * 16;
    const float* src = W + (size_t)t*65536 + (size_t)(i0 + r)*256 + o0 + c0;
    #pragma unroll
    for (int j = 0; j < 16; j += 4){
        float4 v = *reinterpret_cast<const float4*>(src + j);
        S[r][c0 + j + 0] = v.x; S[r][c0 + j + 1] = v.y;
        S[r][c0 + j + 2] = v.z; S[r][c0 + j + 3] = v.w;
    }
    __syncthreads();
    unsigned short tmp[16];
    #pragma unroll
    for (int j = 0; j < 16; j++) tmp[j] = f2bf(S[c0 + j][r]);
    unsigned short* dst = Wt + (size_t)t*65536 + (size_t)(o0 + r)*256 + i0 + c0;
    *reinterpret_cast<uint4*>(dst)     = *reinterpret_cast<uint4*>(tmp);
    *reinterpret_cast<uint4*>(dst + 8) = *reinterpret_cast<uint4*>(tmp + 8);
}

// rte_vec[m,i] = sum_j emb[m,j]*rte_W[i,j] + rte_b[i]
__global__ void k_rtevec(const float* __restrict__ emb, const float* __restrict__ W,
                         const float* __restrict__ b, float* __restrict__ out){
    __shared__ float se[DIM];
    int m = blockIdx.x, i = threadIdx.x;
    se[i] = emb[m*DIM + i];
    __syncthreads();
    const float* wr = W + i*DIM;
    float acc = 0.f;
    #pragma unroll 8
    for (int j = 0; j < DIM; j += 4){
        float4 w = *reinterpret_cast<const float4*>(wr + j);
        acc += se[j]*w.x + se[j+1]*w.y + se[j+2]*w.z + se[j+3]*w.w;
    }
    out[m*DIM + i] = acc + b[i];
}

// rte_k[t,m,o] = sum_i rvec[m,i]*Wk[t][i,o]; same for rte_v
__global__ void k_rtekv(const float* __restrict__ rvec, const float* __restrict__ Wk,
                        const float* __restrict__ Wv, float* __restrict__ rk,
                        float* __restrict__ rv){
    __shared__ float sv[DIM];
    int m = blockIdx.x, t = blockIdx.y, o = threadIdx.x;
    sv[o] = rvec[m*DIM + o];
    __syncthreads();
    const float* wk = Wk + (size_t)t*DIM*DIM;
    const float* wv = Wv + (size_t)t*DIM*DIM;
    float ak = 0.f, av = 0.f;
    #pragma unroll 4
    for (int i = 0; i < DIM; i++){
        float s = sv[i];
        ak += s * wk[i*DIM + o];
        av += s * wv[i*DIM + o];
    }
    rk[(t*ML+m)*DIM + o] = ak;
    rv[(t*ML+m)*DIM + o] = av;
}

// two-level bucketing: LDS histogram + one global atomic per (block,key)
__global__ void k_bucket(const int* __restrict__ ntype, const int* __restrict__ etype,
                         int* __restrict__ ncnt, int* __restrict__ nlist,
                         int* __restrict__ ecnt, int* __restrict__ elist){
    __shared__ int lc[8];
    __shared__ int lb[8];
    int tid = threadIdx.x;
    if (tid < 8) lc[tid] = 0;
    __syncthreads();
    int idx = blockIdx.x*256 + tid;
    int key = -1, lpos = 0;
    if (idx < NN){
        key = ntype[idx];
        lpos = atomicAdd(&lc[key], 1);
    } else if (idx < NN + NE){
        key = NT + etype[idx - NN];
        lpos = atomicAdd(&lc[key], 1);
    }
    __syncthreads();
    if (tid < 8 && lc[tid] > 0){
        lb[tid] = atomicAdd(tid < NT ? &ncnt[tid] : &ecnt[tid - NT], lc[tid]);
    }
    __syncthreads();
    if (idx < NN){
        nlist[key*NN + lb[key] + lpos] = idx;
    } else if (idx < NN + NE){
        elist[(key - NT)*NE + lb[key] + lpos] = idx - NN;
    }
}

// -------- MFMA bf16 projection: Y[node,:] = Xb[node,:] @ W_t + bias_t ------
// Xb: [*, 256] bf16 rows gathered via nlist; Wt: [NT][256(o)][256(i)] bf16.
// 128x128 block tile, 2x2 waves, 4x4 16x16x32 fragments, BK=32.
__global__ __launch_bounds__(256) void k_projM(const unsigned short* __restrict__ Xb,
        const int* __restrict__ nlist, const int* __restrict__ ncnt,
        const unsigned short* __restrict__ Wt, const float* __restrict__ bias,
        float* __restrict__ Y){
    __shared__ unsigned short As[128*40];
    __shared__ unsigned short Bs[128*40];
    int t = blockIdx.z;
    int cnt = ncnt[t];
    int m0 = blockIdx.x * 128;
    if (m0 >= cnt) return;
    int o0 = blockIdx.y * 128;
    int th = threadIdx.x;
    const unsigned short* Wtt = Wt + (size_t)t*65536;

    // staging assignment: thread -> (row = th>>1, half = th&1 -> 16 bf16)
    int srow = th >> 1, shalf = th & 1;
    int arow = m0 + srow;
    int anode = (arow < cnt) ? nlist[t*NN + arow] : nlist[t*NN];
    const unsigned short* agp = Xb + (size_t)anode*256 + shalf*16;       // ushort units
    const unsigned short* bgp = Wtt + (size_t)(o0 + srow)*256 + shalf*16;
    uint4* alp = reinterpret_cast<uint4*>(&As[srow*40 + shalf*16]);
    uint4* blp = reinterpret_cast<uint4*>(&Bs[srow*40 + shalf*16]);

    int l = th & 63, w = th >> 6;
    int wm = w >> 1, wn = w & 1;
    int lrow = l & 15, kc = l >> 4;

    f32x4 acc[4][4];
    #pragma unroll
    for (int i = 0; i < 4; i++)
        #pragma unroll
        for (int j = 0; j < 4; j++) acc[i][j] = (f32x4){0.f,0.f,0.f,0.f};

    for (int k0 = 0; k0 < 256; k0 += 32){
        uint4 ga0 = *reinterpret_cast<const uint4*>(agp + k0);
        uint4 ga1 = *reinterpret_cast<const uint4*>(agp + k0 + 8);
        uint4 gb0 = *reinterpret_cast<const uint4*>(bgp + k0);
        uint4 gb1 = *reinterpret_cast<const uint4*>(bgp + k0 + 8);
        __syncthreads();
        alp[0] = ga0; alp[1] = ga1;
        blp[0] = gb0; blp[1] = gb1;
        __syncthreads();
        short8v a[4], b[4];
        #pragma unroll
        for (int mi = 0; mi < 4; mi++)
            a[mi] = *reinterpret_cast<const short8v*>(&As[(wm*64 + mi*16 + lrow)*40 + kc*8]);
        #pragma unroll
        for (int ni = 0; ni < 4; ni++)
            b[ni] = *reinterpret_cast<const short8v*>(&Bs[(wn*64 + ni*16 + lrow)*40 + kc*8]);
        #pragma unroll
        for (int mi = 0; mi < 4; mi++)
            #pragma unroll
            for (int ni = 0; ni < 4; ni++)
                acc[mi][ni] = __builtin_amdgcn_mfma_f32_16x16x32_bf16(a[mi], b[ni], acc[mi][ni], 0, 0, 0);
    }

    // epilogue: C layout col = lane&15, row = (lane>>4)*4 + j  (m89-verified)
    float bv[4];
    #pragma unroll
    for (int ni = 0; ni < 4; ni++)
        bv[ni] = bias[t*256 + o0 + wn*64 + ni*16 + (l & 15)];
    #pragma unroll
    for (int mi = 0; mi < 4; mi++){
        #pragma unroll
        for (int j = 0; j < 4; j++){
            int grow = m0 + wm*64 + mi*16 + (l >> 4)*4 + j;
            if (grow < cnt){
                int node = nlist[t*NN + grow];
                float* yp = Y + (size_t)node*256 + o0 + wn*64 + (l & 15);
                #pragma unroll
                for (int ni = 0; ni < 4; ni++)
                    yp[ni*16] = acc[mi][ni][j] + bv[ni];
            }
        }
    }
}

// pass A: logits + segment max
__global__ __launch_bounds__(256) void k_passA(const float* __restrict__ qn,
        const float* __restrict__ kn, const float* __restrict__ rk,
        const int* __restrict__ elist, const int* __restrict__ ecnt,
        const int* __restrict__ esrc, const int* __restrict__ edst,
        const int* __restrict__ etime, const int* __restrict__ ntype,
        const float* __restrict__ rel_att, const float* __restrict__ rel_pri,
        float* __restrict__ logit, unsigned* __restrict__ mx){
    __shared__ int s_src[64], s_dst[64], s_tm[64], s_st[64], s_eid[64];
    __shared__ float ke[64][36], qe[64][36];
    int r = blockIdx.y;
    int cnt = ecnt[r];
    int e0 = blockIdx.x * 64;
    if (e0 >= cnt) return;
    int nE = min(64, cnt - e0);
    int tid = threadIdx.x;
    if (tid < 64){
        int e = elist[r*NE + e0 + (tid < nE ? tid : 0)];
        int sj = esrc[e];
        s_eid[tid] = e; s_src[tid] = sj; s_dst[tid] = edst[e];
        s_tm[tid] = etime[e]; s_st[tid] = ntype[sj];
    }
    __syncthreads();
    int f = tid & 31, mg = tid >> 5;
    const float inv = 0.17677669529663687f;  // 1/sqrt(32)
    for (int h = 0; h < NH; h++){
        #pragma unroll
        for (int u = 0; u < 2; u++){
            int fi = tid + u*256;
            int m = fi >> 3, c4 = (fi & 7) * 4;
            float4 kv = *reinterpret_cast<const float4*>(kn + (size_t)s_src[m]*DIM + h*32 + c4);
            float4 rvv = *reinterpret_cast<const float4*>(rk + (size_t)(s_st[m]*ML + s_tm[m])*DIM + h*32 + c4);
            float4 qv = *reinterpret_cast<const float4*>(qn + (size_t)s_dst[m]*DIM + h*32 + c4);
            kv.x += rvv.x; kv.y += rvv.y; kv.z += rvv.z; kv.w += rvv.w;
            *reinterpret_cast<float4*>(&ke[m][c4]) = kv;
            *reinterpret_cast<float4*>(&qe[m][c4]) = qv;
        }
        __syncthreads();
        float rf[32];
        const float* relb = rel_att + (size_t)(r*NH + h)*1024;
        #pragma unroll
        for (int d = 0; d < 32; d++) rf[d] = relb[d*32 + f];
        float pri = rel_pri[r*NH + h] * inv;
        #pragma unroll
        for (int mi = 0; mi < 8; mi++){
            int m = mg*8 + mi;
            float acc = 0.f;
            #pragma unroll
            for (int d4 = 0; d4 < 8; d4++){
                float4 k4 = *reinterpret_cast<const float4*>(&ke[m][d4*4]);
                acc += k4.x*rf[d4*4] + k4.y*rf[d4*4+1] + k4.z*rf[d4*4+2] + k4.w*rf[d4*4+3];
            }
            float v = acc * qe[m][f];
            v += __shfl_xor(v, 1);
            v += __shfl_xor(v, 2);
            v += __shfl_xor(v, 4);
            v += __shfl_xor(v, 8);
            v += __shfl_xor(v, 16);
            if (f == 0 && m < nE){
                float lv = v * pri;
                logit[(size_t)s_eid[m]*NH + h] = lv;
                atomicMax(&mx[s_dst[m]*NH + h], fkey(lv));
            }
        }
        __syncthreads();
    }
}

// pass B: unnormalized exp-weighted message aggregation + denominator
__global__ __launch_bounds__(256) void k_passB(const float* __restrict__ vn,
        const float* __restrict__ rv, const int* __restrict__ elist,
        const int* __restrict__ ecnt, const int* __restrict__ esrc,
        const int* __restrict__ edst, const int* __restrict__ etime,
        const int* __restrict__ ntype, const float* __restrict__ rel_msg,
        const float* __restrict__ logit, const unsigned* __restrict__ mx,
        float* __restrict__ den, float* __restrict__ aggr){
    __shared__ int s_src[64], s_dst[64], s_tm[64], s_st[64], s_eid[64];
    __shared__ float ve[64][36];
    int r = blockIdx.y;
    int cnt = ecnt[r];
    int e0 = blockIdx.x * 64;
    if (e0 >= cnt) return;
    int nE = min(64, cnt - e0);
    int tid = threadIdx.x;
    if (tid < 64){
        int e = elist[r*NE + e0 + (tid < nE ? tid : 0)];
        int sj = esrc[e];
        s_eid[tid] = e; s_src[tid] = sj; s_dst[tid] = edst[e];
        s_tm[tid] = etime[e]; s_st[tid] = ntype[sj];
    }
    __syncthreads();
    int f = tid & 31, mg = tid >> 5;
    for (int h = 0; h < NH; h++){
        #pragma unroll
        for (int u = 0; u < 2; u++){
            int fi = tid + u*256;
            int m = fi >> 3, c4 = (fi & 7) * 4;
            float4 vv = *reinterpret_cast<const float4*>(vn + (size_t)s_src[m]*DIM + h*32 + c4);
            float4 rr = *reinterpret_cast<const float4*>(rv + (size_t)(s_st[m]*ML + s_tm[m])*DIM + h*32 + c4);
            vv.x += rr.x; vv.y += rr.y; vv.z += rr.z; vv.w += rr.w;
            *reinterpret_cast<float4*>(&ve[m][c4]) = vv;
        }
        __syncthreads();
        float rf[32];
        const float* relb = rel_msg + (size_t)(r*NH + h)*1024;
        #pragma unroll
        for (int d = 0; d < 32; d++) rf[d] = relb[d*32 + f];
        #pragma unroll
        for (int mi = 0; mi < 8; mi++){
            int m = mg*8 + mi;
            float acc = 0.f;
            #pragma unroll
            for (int d4 = 0; d4 < 8; d4++){
                float4 v4 = *reinterpret_cast<const float4*>(&ve[m][d4*4]);
                acc += v4.x*rf[d4*4] + v4.y*rf[d4*4+1] + v4.z*rf[d4*4+2] + v4.w*rf[d4*4+3];
            }
            if (m < nE){
                float lg = logit[(size_t)s_eid[m]*NH + h];
                float mv = funkey(mx[s_dst[m]*NH + h]);
                float ex = __expf(lg - mv);
                atomicAdd(&aggr[(size_t)s_dst[m]*DIM + h*32 + f], acc*ex);
                if (f == 0) atomicAdd(&den[s_dst[m]*NH + h], ex);
            }
        }
        __syncthreads();
    }
}

__global__ void k_aggdiv(float* __restrict__ aggr, const float* __restrict__ den){
    int idx = blockIdx.x*256 + threadIdx.x;
    int n = idx >> 8, c = idx & 255;
    float d = den[n*NH + (c >> 5)];
    if (d > 0.f) aggr[idx] /= d;
}

__global__ __launch_bounds__(256) void k_epi(const float* __restrict__ trans,
        const float* __restrict__ x, const int* __restrict__ ntype,
        const float* __restrict__ skip, const float* __restrict__ g,
        const float* __restrict__ b, float* __restrict__ out){
    __shared__ float r1[4], r2[4];
    int n = blockIdx.x, c = threadIdx.x;
    int t = ntype[n];
    float alpha = 1.f / (1.f + expf(-skip[t]));
    float mixed = trans[(size_t)n*DIM + c]*alpha + x[(size_t)n*DIM + c]*(1.f - alpha);
    float s = mixed, q = mixed*mixed;
    #pragma unroll
    for (int off = 32; off >= 1; off >>= 1){
        s += __shfl_down(s, off);
        q += __shfl_down(q, off);
    }
    int w = c >> 6;
    if ((c & 63) == 0){ r1[w] = s; r2[w] = q; }
    __syncthreads();
    float S  = r1[0]+r1[1]+r1[2]+r1[3];
    float S2 = r2[0]+r2[1]+r2[2]+r2[3];
    float mu = S * (1.f/DIM);
    float var = S2 * (1.f/DIM) - mu*mu;
    out[(size_t)n*DIM + c] = (mixed - mu) * rsqrtf(var + EPSF) * g[t*DIM + c] + b[t*DIM + c];
}

extern "C" void kernel_launch(void* const* d_in, const int* in_sizes, int n_in,
                              void* d_out, int out_size, void* d_ws, size_t ws_size,
                              hipStream_t stream){
    const float* node_inp = (const float*)d_in[0];
    const float* Wk  = (const float*)d_in[1];
    const float* bk  = (const float*)d_in[2];
    const float* Wq  = (const float*)d_in[3];
    const float* bq  = (const float*)d_in[4];
    const float* Wv  = (const float*)d_in[5];
    const float* bv  = (const float*)d_in[6];
    const float* Wa  = (const float*)d_in[7];
    const float* ba  = (const float*)d_in[8];
    const float* ln_g = (const float*)d_in[9];
    const float* ln_b = (const float*)d_in[10];
    const float* rel_pri = (const float*)d_in[11];
    const float* rel_att = (const float*)d_in[12];
    const float* rel_msg = (const float*)d_in[13];
    const float* skip  = (const float*)d_in[14];
    const float* rte_W = (const float*)d_in[15];
    const float* rte_b = (const float*)d_in[16];
    const float* rte_emb = (const float*)d_in[17];
    const int* ntype = (const int*)d_in[18];
    const int* eidx  = (const int*)d_in[19];
    const int* etype = (const int*)d_in[20];
    const int* etime = (const int*)d_in[21];
    const int* esrc = eidx;
    const int* edst = eidx + NE;

    float* ws = (float*)d_ws;
    size_t o_aggr = 0;
    size_t o_mx   = o_aggr + (size_t)NN*DIM;
    size_t o_den  = o_mx   + (size_t)NN*NH;
    size_t o_cnt  = o_den  + (size_t)NN*NH;
    size_t zeroEnd= o_cnt  + 16;
    size_t o_q    = zeroEnd + 16;
    size_t o_k    = o_q    + (size_t)NN*DIM;
    size_t o_rvec = o_k    + (size_t)NN*DIM;
    size_t o_rk   = o_rvec + (size_t)ML*DIM;
    size_t o_rv   = o_rk   + (size_t)NT*ML*DIM;
    size_t o_logit= o_rv   + (size_t)NT*ML*DIM;
    size_t o_nlist= o_logit+ (size_t)NE*NH;
    size_t o_elist= o_nlist+ (size_t)NT*NN;

    float* aggr = ws + o_aggr;
    unsigned* mx = (unsigned*)(ws + o_mx);
    float* den = ws + o_den;
    int* ncnt = (int*)(ws + o_cnt);
    int* ecnt = ncnt + 8;
    float* qn = ws + o_q;
    float* kn = ws + o_k;
    float* rvec = ws + o_rvec;
    float* rk = ws + o_rk;
    float* rv = ws + o_rv;
    float* logit = ws + o_logit;
    int* nlist = (int*)(ws + o_nlist);
    int* elist = (int*)(ws + o_elist);
    float* vn = qn;      // alias: q dead after pass A
    float* trans = qn;   // alias: v dead after pass B
    float* out = (float*)d_out;

    // d_out doubles as pre-epilogue scratch: bf16 x (7.68M ushort) + bf16 W^T (4x 196608 ushort)
    unsigned short* xb  = (unsigned short*)d_out;
    unsigned short* wtb = (unsigned short*)((float*)d_out + (size_t)NN*DIM/2);
    unsigned short* wtq = wtb;
    unsigned short* wtk = wtb + 1*(size_t)NT*DIM*DIM;
    unsigned short* wtv = wtb + 2*(size_t)NT*DIM*DIM;
    unsigned short* wta = wtb + 3*(size_t)NT*DIM*DIM;
    unsigned short* aggr_bf = (unsigned short*)kn;   // kn dead after passA

    hipMemsetAsync(d_ws, 0, zeroEnd * sizeof(float), stream);
    k_cvt<<<NN*DIM/(8*256), 256, 0, stream>>>(node_inp, xb);
    dim3 wgrid(4, 4, NT);
    k_cvt_w<<<wgrid, 256, 0, stream>>>(Wq, wtq);
    k_cvt_w<<<wgrid, 256, 0, stream>>>(Wk, wtk);
    k_cvt_w<<<wgrid, 256, 0, stream>>>(Wv, wtv);
    k_cvt_w<<<wgrid, 256, 0, stream>>>(Wa, wta);
    k_rtevec<<<ML, 256, 0, stream>>>(rte_emb, rte_W, rte_b, rvec);
    k_rtekv<<<dim3(ML, NT), 256, 0, stream>>>(rvec, Wk, Wv, rk, rv);
    k_bucket<<<(NN+NE+255)/256, 256, 0, stream>>>(ntype, etype, ncnt, nlist, ecnt, elist);

    dim3 pgrid((NN+127)/128, 2, NT);
    k_projM<<<pgrid, 256, 0, stream>>>(xb, nlist, ncnt, wtq, bq, qn);
    k_projM<<<pgrid, 256, 0, stream>>>(xb, nlist, ncnt, wtk, bk, kn);
    dim3 egrid((NE+63)/64, NR);
    k_passA<<<egrid, 256, 0, stream>>>(qn, kn, rk, elist, ecnt, esrc, edst, etime, ntype,
                                       rel_att, rel_pri, logit, mx);
    k_projM<<<pgrid, 256, 0, stream>>>(xb, nlist, ncnt, wtv, bv, vn);
    k_passB<<<egrid, 256, 0, stream>>>(vn, rv, elist, ecnt, esrc, edst, etime, ntype,
                                       rel_msg, logit, mx, den, aggr);
    k_aggdiv<<<(NN*DIM)/256, 256, 0, stream>>>(aggr, den);
    k_cvt<<<NN*DIM/(8*256), 256, 0, stream>>>(aggr, aggr_bf);
    k_projM<<<pgrid, 256, 0, stream>>>(aggr_bf, nlist, ncnt, wta, ba, trans);
    k_epi<<<NN, 256, 0, stream>>>(trans, node_inp, ntype, skip, ln_g, ln_b, out);
}